// Round 15
// baseline (72.352 us; speedup 1.0000x reference)
//
#include <hip/hip_runtime.h>
#include <math.h>

// ---------------------------------------------------------------------------
// SimpleTernaryNet forward, MFMA-f16 for conv1 + conv2 + fc1.
//   tern(w) -> conv3x3(3->16)+b+relu -> maxpool2      (f16 MFMA, 9-row K=27)
//           -> conv3x3(16->32)+b+relu -> maxpool2     (f16 MFMA, 9-shift)
//           -> fc(2048->128)+b+relu                   (f16 MFMA, LDS-staged A,
//                                                      4Kx4N waves, 1-shot reduce)
//           -> fc(128->10)+b                          (fp32 VALU)
//
// Round-15: fc restructured. Round-14 budget put fc at ~28us vs ~6us roofline;
// suspected cause: fragment-strided A-loads (16x64B scattered txns/wave-load,
// HBM-cold) + 8-barrier/64KB tree reduction. New fc: block A-tile staged in
// LDS via coalesced float4 (2x32KB halves), waves = 4 K-chunks x 4 N-groups,
// single-shot 24KB partial dump (1 barrier) instead of 4-round tree.
// conv12 / ternarize byte-identical to round 14 (verified 71.2us).
//
// ws layout (bytes):
//   [0)         tw1f   f16 [3][64][4] conv1 B-frags   1536 B
//   [1536)      tw2f   f16 [9][2][64][4] conv2 B-frags 9216 B
//   [10752)     twf1   f16 [128 n][2048 k] SIGN-ONLY  524288 B
//   [535040)    twf2   f32 [10][128]                  5120 B
//   [540160)    h2p    f16 [4096][2048]               16777216 B
//   [17317376)  partials f32 sum[64], sa[64], cnt[64]
// ---------------------------------------------------------------------------

typedef _Float16 half2v __attribute__((ext_vector_type(2)));
typedef _Float16 half4  __attribute__((ext_vector_type(4)));
typedef _Float16 half8  __attribute__((ext_vector_type(8)));
typedef float    f32x4  __attribute__((ext_vector_type(4)));
typedef unsigned u32x2  __attribute__((ext_vector_type(2)));

#define WF1_N 262144
#define WF1_SLICES 64
#define WF1_SLICE 4096

__device__ __forceinline__ float block_reduce_256(float v, float* red, int t) {
    red[t] = v; __syncthreads();
    for (int o = 128; o > 0; o >>= 1) {
        if (t < o) red[t] += red[t + o];
        __syncthreads();
    }
    float r = red[0]; __syncthreads();
    return r;
}

__device__ __forceinline__ float wave_sum64(float v) {
#pragma unroll
    for (int o = 32; o > 0; o >>= 1) v += __shfl_xor(v, o);
    return v;
}

__device__ __forceinline__ unsigned pk16(float a, float b) {
    half2v h;
    h[0] = (_Float16)a;
    h[1] = (_Float16)b;
    return __builtin_bit_cast(unsigned, h);
}

// ---------------- stage A: wf1 partial |sum| + small tensors complete ------
__global__ void tern_stageA(const float* __restrict__ w1,
                            const float* __restrict__ w2,
                            const float* __restrict__ wf1,
                            const float* __restrict__ wf2,
                            _Float16* __restrict__ tw1f,
                            _Float16* __restrict__ tw2f,
                            float* __restrict__ twf2,
                            float* __restrict__ part_sum) {
    __shared__ float red[256];
    const int t = threadIdx.x;
    const int bid = blockIdx.x;

    if (bid < WF1_SLICES) {
        const float4* src = reinterpret_cast<const float4*>(wf1 + (size_t)bid * WF1_SLICE);
        float s = 0.f;
#pragma unroll
        for (int j = 0; j < 4; ++j) {
            const float4 v = src[t + j * 256];
            s += fabsf(v.x) + fabsf(v.y) + fabsf(v.z) + fabsf(v.w);
        }
        const float tot = block_reduce_256(s, red, t);
        if (t == 0) part_sum[bid] = tot;
        return;
    }

    const float* w;
    int n;
    const int which = bid - WF1_SLICES;  // 0:w1 1:w2 2:wf2
    switch (which) {
        case 0: w = w1;  n = 432;  break;
        case 1: w = w2;  n = 4608; break;
        default: w = wf2; n = 1280; break;
    }
    float s = 0.f;
    for (int i = t; i < n; i += 256) s += fabsf(w[i]);
    const float delta = 0.7f * block_reduce_256(s, red, t) / (float)n;
    float sa = 0.f, cnt = 0.f;
    for (int i = t; i < n; i += 256) {
        float a = fabsf(w[i]);
        if (a > delta) { sa += a; cnt += 1.f; }
    }
    const float tot_sa = block_reduce_256(sa, red, t);
    const float tot_cnt = block_reduce_256(cnt, red, t);
    const float alpha = tot_sa / fmaxf(tot_cnt, 1.0f);

    switch (which) {
        case 0:
            // conv1 B-frags (K=16): o=(m*64+l)*4+j; rho=m*4+(l>>4); co=l&15
            for (int o = t; o < 768; o += 256) {
                int j = o & 3;
                int l = (o >> 2) & 63;
                int m = o >> 8;
                int rho = m * 4 + (l >> 4);
                int co = l & 15;
                float v = 0.f;
                if (rho < 9 && j < 3) {
                    float wv = w1[co * 27 + (rho / 3) * 9 + (rho % 3) * 3 + j];
                    v = (fabsf(wv) > delta) ? copysignf(alpha, wv) : 0.f;
                }
                tw1f[o] = (_Float16)v;
            }
            break;
        case 1:
            // conv2 B-frags (K=16): o=((s*2+nt)*64+l)*4+j; ci=(l>>4)*4+j;
            // co=(l&15)+nt*16
            for (int o = t; o < 4608; o += 256) {
                int j  = o & 3;
                int ll = (o >> 2) & 63;
                int nt = (o >> 8) & 1;
                int s9 = o >> 9;
                int ci = (ll >> 4) * 4 + j;
                int co = (ll & 15) + nt * 16;
                float wv = w2[(co * 16 + ci) * 9 + s9];
                float v = (fabsf(wv) > delta) ? copysignf(alpha, wv) : 0.f;
                tw2f[o] = (_Float16)v;
            }
            break;
        default:
            for (int o = t; o < 1280; o += 256) {
                float wv = wf2[o];
                twf2[o] = (fabsf(wv) > delta) ? copysignf(alpha, wv) : 0.f;
            }
            break;
    }
}

// ---------------- stage B: delta + masked partials + SIGN write ------------
// Writes twf1 = sign(w)*mask as f16 (+-1/0, exact); alpha applied in fc.
__global__ void tern_stageB(const float* __restrict__ wf1,
                            const float* __restrict__ part_sum,
                            float* __restrict__ part_sa,
                            float* __restrict__ part_cnt,
                            _Float16* __restrict__ twf1) {
    __shared__ float red[256];
    const int t = threadIdx.x;
    const int bid = blockIdx.x;

    float v = (t < WF1_SLICES) ? part_sum[t] : 0.f;
    const float delta = 0.7f * block_reduce_256(v, red, t) / (float)WF1_N;

    const float4* src = reinterpret_cast<const float4*>(wf1 + (size_t)bid * WF1_SLICE);
    half4* dst = reinterpret_cast<half4*>(twf1 + (size_t)bid * WF1_SLICE);
    float sa = 0.f, cnt = 0.f;
#pragma unroll
    for (int j = 0; j < 4; ++j) {
        const float4 w4 = src[t + j * 256];
        half4 hv;
        float a;
        a = fabsf(w4.x); if (a > delta) { sa += a; cnt += 1.f; }
        hv[0] = (_Float16)((fabsf(w4.x) > delta) ? copysignf(1.0f, w4.x) : 0.f);
        a = fabsf(w4.y); if (a > delta) { sa += a; cnt += 1.f; }
        hv[1] = (_Float16)((fabsf(w4.y) > delta) ? copysignf(1.0f, w4.y) : 0.f);
        a = fabsf(w4.z); if (a > delta) { sa += a; cnt += 1.f; }
        hv[2] = (_Float16)((fabsf(w4.z) > delta) ? copysignf(1.0f, w4.z) : 0.f);
        a = fabsf(w4.w); if (a > delta) { sa += a; cnt += 1.f; }
        hv[3] = (_Float16)((fabsf(w4.w) > delta) ? copysignf(1.0f, w4.w) : 0.f);
        dst[t + j * 256] = hv;
    }
    const float tot_sa = block_reduce_256(sa, red, t);
    const float tot_cnt = block_reduce_256(cnt, red, t);
    if (t == 0) { part_sa[bid] = tot_sa; part_cnt[bid] = tot_cnt; }
}

// ---------------- fused conv1(MFMA)+pool + conv2(MFMA)+pool ----------------
// H1P=18: pixel stride 9 dwords (odd) -> conv2 A-read bank conflicts 2-way (free).
#define H1P 18
#define PSZ 3472          // 3*34*34=3468 + 4 pad f16 (6944 B, /16 ok)
#define H1SZ (18*18*H1P)  // 5832 f16 = 11664 B (/16 ok)

__global__ __launch_bounds__(256, 5)
void conv12_kernel(const float* __restrict__ x,      // [B,3,32,32]
                   const float* __restrict__ b1,     // [16]
                   const float* __restrict__ b2,     // [32]
                   const _Float16* __restrict__ tw1f,// [3][64][4] f16 B-frags
                   const _Float16* __restrict__ tw2f,// [9][2][64][4] f16 B-frags
                   _Float16* __restrict__ h2p) {     // [B,2048] f16
    __shared__ __align__(16) _Float16 PA[PSZ];          // planar f16 [3][34][34]
    __shared__ __align__(16) _Float16 PB[PSZ];          // PB[i] = PA[i+1]
    __shared__ __align__(16) _Float16 h1s[H1SZ];        // (y*18+x)*18 + ci
    __shared__ __align__(16) _Float16 h2s[2048];        // co*64 + py*8 + px
    __shared__ float b1s[16], b2s[32];

    const int t = threadIdx.x;
    const int b = blockIdx.x;
    const int wid = t >> 6, l = t & 63;

    // issue x loads FIRST (3x float4, coalesced) so HBM latency hides
    // under the zero phase
    float4 xv4[3];
    {
        const float4* xb4 = reinterpret_cast<const float4*>(x + (size_t)b * 3072);
#pragma unroll
        for (int j = 0; j < 3; ++j) xv4[j] = xb4[t + j * 256];
    }
    // conv1 B-frags (L2-resident)
    half4 bfr1[3];
#pragma unroll
    for (int m = 0; m < 3; ++m)
        bfr1[m] = *reinterpret_cast<const half4*>(tw1f + (size_t)(m * 64 + l) * 4);
    if (t < 16) b1s[t] = b1[t];
    if (t < 32) b2s[t] = b2[t];

    // zero LDS via float4 (halos / garbage-tap safety)
    {
        const float4 z = {0.f, 0.f, 0.f, 0.f};
        float4* pa4 = reinterpret_cast<float4*>(PA);
        float4* pb4 = reinterpret_cast<float4*>(PB);
        float4* h14 = reinterpret_cast<float4*>(h1s);
        for (int i = t; i < PSZ * 2 / 16; i += 256) { pa4[i] = z; pb4[i] = z; }
        for (int i = t; i < H1SZ * 2 / 16; i += 256) h14[i] = z;
    }
    __syncthreads();

    // phase 1: stage x -> planar f16 PA + shifted copy PB (parity-aware u32)
    {
#pragma unroll
        for (int j = 0; j < 3; ++j) {
            const int f = t + j * 256;           // float4 group id, 768 total
            const int c = f >> 8, rem = f & 255;
            const int iy = rem >> 3, ix = (rem & 7) << 2;
            const int idx = ((c * 34) + iy + 1) * 34 + 1 + ix;
            const float4 v = xv4[j];
            const unsigned w0 = __builtin_bit_cast(unsigned, __builtin_amdgcn_cvt_pkrtz(v.x, v.y));
            const unsigned w1 = __builtin_bit_cast(unsigned, __builtin_amdgcn_cvt_pkrtz(v.z, v.w));
            const half2v h0 = __builtin_bit_cast(half2v, w0);
            const half2v h1 = __builtin_bit_cast(half2v, w1);
            *reinterpret_cast<unsigned*>(&PB[idx - 1]) = w0;
            *reinterpret_cast<unsigned*>(&PB[idx + 1]) = w1;
            PA[idx] = h0[0];
            *reinterpret_cast<unsigned*>(&PA[idx + 1]) = (w0 >> 16) | (w1 << 16);
            PA[idx + 3] = h1[1];
        }
    }
    __syncthreads();

    // phase 2: conv1 via 3x chained 16x16x16 MFMA (K-rows (c,ky) x 4 taps)
    {
        const int r15 = l & 15, g = l >> 4;
        const int p = r15 & 1;
        int laneIdx[3];
#pragma unroll
        for (int m = 0; m < 3; ++m) {
            int rho = m * 4 + g;
            if (rho > 8) rho = 0;  // dead rows: B is zero there, any finite read ok
            const int c = rho / 3, ky = rho % 3;
            laneIdx[m] = ((c * 34 + ky) * 34 + r15 - p) >> 1;
        }
        const unsigned* basep = p ? reinterpret_cast<const unsigned*>(PB)
                                  : reinterpret_cast<const unsigned*>(PA);
        const float bia = b1s[r15];

#pragma unroll 1
        for (int i = 0; i < 8; ++i) {
            const int P = wid * 8 + i;
            const int py = P >> 1, xh = P & 1;
            const int x0 = xh * 16;
            f32x4 accA = {0.f, 0.f, 0.f, 0.f};
            f32x4 accB = {0.f, 0.f, 0.f, 0.f};
#pragma unroll
            for (int h2 = 0; h2 < 2; ++h2) {
                const int y = 2 * py + h2;
                const int uoff = (y * 34 + x0) >> 1;
                f32x4 acc = {0.f, 0.f, 0.f, 0.f};
#pragma unroll
                for (int m = 0; m < 3; ++m) {
                    const unsigned* q = basep + laneIdx[m] + uoff;
                    u32x2 d;
                    d.x = q[0];
                    d.y = q[1];
                    const half4 a = __builtin_bit_cast(half4, d);
                    acc = __builtin_amdgcn_mfma_f32_16x16x16f16(a, bfr1[m], acc, 0, 0, 0);
                }
                if (h2 == 0) accA = acc; else accB = acc;
            }
            // 2x2 maxpool on regs (x = g*4 + reg), then bias+relu
            float e0 = fmaxf(fmaxf(accA[0], accA[1]), fmaxf(accB[0], accB[1]));
            float e1 = fmaxf(fmaxf(accA[2], accA[3]), fmaxf(accB[2], accB[3]));
            e0 = fmaxf(e0 + bia, 0.f);
            e1 = fmaxf(e1 + bia, 0.f);
            const int px0 = xh * 8 + g * 2;
            const int pix = (py + 1) * 18 + (px0 + 1);
            h1s[pix * H1P + r15]       = (_Float16)e0;
            h1s[(pix + 1) * H1P + r15] = (_Float16)e1;
        }
    }

    // conv2 B-frags (global, per-lane 8B, coalesced, L2-resident)
    half4 bfr[9][2];
#pragma unroll
    for (int s = 0; s < 9; ++s)
#pragma unroll
        for (int nt = 0; nt < 2; ++nt)
            bfr[s][nt] = *reinterpret_cast<const half4*>(
                tw2f + (size_t)((s * 2 + nt) * 64 + l) * 4);
    __syncthreads();

    // phase 3: conv2 (9-shift MFMA) + bias + relu + pool
    {
        const int xq = l & 15, g = l >> 4;
        const unsigned* h1u = reinterpret_cast<const unsigned*>(h1s);
        float sav[2][2];
#pragma unroll
        for (int yy = 0; yy < 4; ++yy) {
            const int y = wid * 4 + yy;
            // per-lane base; all 9 taps are constant dword offsets from here
            const unsigned* qb = h1u + (y * 18 + xq) * 9 + g * 2;
            f32x4 acc0 = {0.f, 0.f, 0.f, 0.f};
            f32x4 acc1 = {0.f, 0.f, 0.f, 0.f};
#pragma unroll
            for (int s = 0; s < 9; ++s) {
                const int dy = s / 3, dx = s % 3;
                const int off = (dy * 18 + dx) * 9;
                u32x2 d;
                d.x = qb[off];
                d.y = qb[off + 1];
                const half4 a = __builtin_bit_cast(half4, d);
                acc0 = __builtin_amdgcn_mfma_f32_16x16x16f16(a, bfr[s][0], acc0, 0, 0, 0);
                acc1 = __builtin_amdgcn_mfma_f32_16x16x16f16(a, bfr[s][1], acc1, 0, 0, 0);
            }
            // x-pool: lane regs are pixels x = g*4 + r
            const float p00 = fmaxf(acc0[0], acc0[1]);
            const float p01 = fmaxf(acc0[2], acc0[3]);
            const float p10 = fmaxf(acc1[0], acc1[1]);
            const float p11 = fmaxf(acc1[2], acc1[3]);
            if ((yy & 1) == 0) {
                sav[0][0] = p00; sav[0][1] = p01;
                sav[1][0] = p10; sav[1][1] = p11;
            } else {
                const int py = (wid * 4 + yy) >> 1;
                const float v00 = fmaxf(fmaxf(sav[0][0], p00) + b2s[xq], 0.f);
                const float v01 = fmaxf(fmaxf(sav[0][1], p01) + b2s[xq], 0.f);
                const float v10 = fmaxf(fmaxf(sav[1][0], p10) + b2s[xq + 16], 0.f);
                const float v11 = fmaxf(fmaxf(sav[1][1], p11) + b2s[xq + 16], 0.f);
                unsigned* h2u = reinterpret_cast<unsigned*>(h2s);
                h2u[xq * 32 + py * 4 + g]        = pk16(v00, v01);
                h2u[(xq + 16) * 32 + py * 4 + g] = pk16(v10, v11);
            }
        }
    }
    __syncthreads();

    // phase 4: h2s -> global (coalesced 16B/thread)
    {
        const float4 v = reinterpret_cast<const float4*>(h2s)[t];
        reinterpret_cast<float4*>(h2p + (size_t)b * 2048)[t] = v;
    }
}

// ---------------- fc1 (MFMA f16, LDS-staged A) + fc2 fused -----------------
// grid = B/16 = 256 blocks x 1024 threads (16 waves = 4 K-chunks x 4 N-groups).
// A-tile (16x2048) staged in LDS via coalesced float4 loads, two 1024-k
// halves reusing one 33KB buffer. Wave (kq,ng): N-cols [ng*32,(ng+1)*32),
// K [kq*256,(kq+1)*256) per half. Single-shot partial dump (24KB, 1 barrier)
// replaces the 4-round tree. twf1 = signs; alpha applied in epilogue.
#define FC_PAD 8  // As row stride 1032 f16 = 516 dwords = 4 mod 32 -> 2-way (free)

__global__ __launch_bounds__(1024, 2)
void fc_kernel(const _Float16* __restrict__ h2p,   // [B,2048]
               const _Float16* __restrict__ twf1,  // [128 n][2048 k] signs
               const float* __restrict__ part_sa,  // [64]
               const float* __restrict__ part_cnt, // [64]
               const float* __restrict__ bf1,      // [128]
               const float* __restrict__ twf2,     // [10][128]
               const float* __restrict__ bf2,      // [10]
               float* __restrict__ out) {          // [B,10]
    __shared__ __align__(16) _Float16 As[16][1024 + FC_PAD];  // 33024 B
    __shared__ float red[4][3][2][256];                       // 24576 B
    __shared__ float Hs[16][132];                             // 8448 B

    const int t = threadIdx.x;
    const int wid = t >> 6, l = t & 63;
    const int kq = wid & 3, ng = wid >> 2;
    const int lx = l & 15, g = l >> 4;
    const int m0 = blockIdx.x * 16;

    // alpha for wf1 (f32 exact; cheap, all waves)
    const float alphaW = wave_sum64(part_sa[l]) / fmaxf(wave_sum64(part_cnt[l]), 1.0f);

    f32x4 acc[2];
    acc[0] = (f32x4){0.f, 0.f, 0.f, 0.f};
    acc[1] = (f32x4){0.f, 0.f, 0.f, 0.f};

    const int stg_r = t >> 7;            // 0..7
    const int stg_c = (t & 127) * 8;     // 0..1016

#pragma unroll
    for (int h = 0; h < 2; ++h) {
        if (h) __syncthreads();  // previous half's reads done before overwrite
        // stage 16 rows x 1024 k, fully coalesced (128 thr/row, 16B each)
#pragma unroll
        for (int p = 0; p < 2; ++p) {
            const int r = stg_r + p * 8;
            *reinterpret_cast<float4*>(&As[r][stg_c]) =
                *reinterpret_cast<const float4*>(
                    h2p + (size_t)(m0 + r) * 2048 + h * 1024 + stg_c);
        }
        __syncthreads();
#pragma unroll
        for (int it = 0; it < 8; ++it) {
            const int kk = kq * 256 + it * 32;
            const half8 a = *reinterpret_cast<const half8*>(&As[lx][kk + g * 8]);
#pragma unroll
            for (int nt = 0; nt < 2; ++nt) {
                const half8 bb = *reinterpret_cast<const half8*>(
                    twf1 + (size_t)(ng * 32 + nt * 16 + lx) * 2048 + h * 1024 + kk + g * 8);
                acc[nt] = __builtin_amdgcn_mfma_f32_16x16x32_f16(a, bb, acc[nt], 0, 0, 0);
            }
        }
    }

    // single-shot partial dump: kq=1..3 write, kq=0 sums
    if (kq != 0) {
#pragma unroll
        for (int nt = 0; nt < 2; ++nt)
            *reinterpret_cast<f32x4*>(&red[ng][kq - 1][nt][l * 4]) = acc[nt];
    }
    __syncthreads();
    if (kq == 0) {
#pragma unroll
        for (int nt = 0; nt < 2; ++nt) {
#pragma unroll
            for (int q = 0; q < 3; ++q)
                acc[nt] += *reinterpret_cast<const f32x4*>(&red[ng][q][nt][l * 4]);
            const int col = ng * 32 + nt * 16 + lx;
            const float bias = bf1[col];
#pragma unroll
            for (int r = 0; r < 4; ++r)
                Hs[g * 4 + r][col] = fmaxf(acc[nt][r] * alphaW + bias, 0.f);
        }
    }
    __syncthreads();

    // fc2: 160 outputs (16 rows x 10)
    if (t < 160) {
        const int m = t / 10, n = t % 10;
        float a = bf2[n];
#pragma unroll 8
        for (int k = 0; k < 128; ++k) a += Hs[m][k] * twf2[n * 128 + k];
        out[(size_t)(m0 + m) * 10 + n] = a;
    }
}

// ---------------------------------------------------------------------------
extern "C" void kernel_launch(void* const* d_in, const int* in_sizes, int n_in,
                              void* d_out, int out_size, void* d_ws, size_t ws_size,
                              hipStream_t stream) {
    const float* x   = (const float*)d_in[0];
    const float* w1  = (const float*)d_in[1];
    const float* b1  = (const float*)d_in[2];
    const float* w2  = (const float*)d_in[3];
    const float* b2  = (const float*)d_in[4];
    const float* wf1 = (const float*)d_in[5];
    const float* bf1 = (const float*)d_in[6];
    const float* wf2 = (const float*)d_in[7];
    const float* bf2 = (const float*)d_in[8];
    float* out = (float*)d_out;
    const int B = in_sizes[0] / (3 * 32 * 32);  // 4096

    char* ws = (char*)d_ws;
    _Float16*  tw1f  = (_Float16*)(ws + 0);
    _Float16*  tw2f  = (_Float16*)(ws + 1536);
    _Float16*  twf1  = (_Float16*)(ws + 10752);
    float*     twf2  = (float*)(ws + 535040);
    _Float16*  h2p   = (_Float16*)(ws + 540160);
    float*     part_sum = (float*)(ws + 17317376);
    float*     part_sa  = part_sum + 64;
    float*     part_cnt = part_sa + 64;

    tern_stageA<<<WF1_SLICES + 3, 256, 0, stream>>>(w1, w2, wf1, wf2,
                                                    tw1f, tw2f, twf2, part_sum);
    tern_stageB<<<WF1_SLICES, 256, 0, stream>>>(wf1, part_sum, part_sa, part_cnt, twf1);
    conv12_kernel<<<B, 256, 0, stream>>>(x, b1, b2, tw1f, tw2f, h2p);
    fc_kernel<<<B / 16, 1024, 0, stream>>>(h2p, twf1, part_sa, part_cnt,
                                           bf1, twf2, bf2, out);
}

// Round 16
// 62.545 us; speedup vs baseline: 1.1568x; 1.1568x over previous
//
#include <hip/hip_runtime.h>
#include <math.h>

// ---------------------------------------------------------------------------
// SimpleTernaryNet forward, MFMA-f16 for conv1 + conv2 + fc1.
//   tern(w) -> conv3x3(3->16)+b+relu -> maxpool2      (f16 MFMA, 9-row K=27)
//           -> conv3x3(16->32)+b+relu -> maxpool2     (f16 MFMA, 9-shift)
//           -> fc(2048->128)+b+relu                   (f16 MFMA, packed-B,
//                                                      LDS-staged A, 4Kx4N)
//           -> fc(128->10)+b                          (fp32 VALU)
//
// Round-16: twf1 now written by tern_stageB in MFMA FRAGMENT ORDER
//   f(n,k) = (k/32)*4096 + (n/16)*512 + ((k>>3)&3)*128 + (n&15)*8 + (k&7)
// so fc's B-loads are lane-linear 16B/lane coalesced (was: 64x16B scattered
// txns per wave-load -> ~4x wasted L2 line bandwidth, the suspected ~15-20us
// of fc's ~25us). conv12 / stageA byte-identical to round 14/15.
//
// ws layout (bytes):
//   [0)         tw1f   f16 [3][64][4] conv1 B-frags   1536 B
//   [1536)      tw2f   f16 [9][2][64][4] conv2 B-frags 9216 B
//   [10752)     twf1   f16 fragment-packed signs      524288 B
//   [535040)    twf2   f32 [10][128]                  5120 B
//   [540160)    h2p    f16 [4096][2048]               16777216 B
//   [17317376)  partials f32 sum[64], sa[64], cnt[64]
// ---------------------------------------------------------------------------

typedef _Float16 half2v __attribute__((ext_vector_type(2)));
typedef _Float16 half4  __attribute__((ext_vector_type(4)));
typedef _Float16 half8  __attribute__((ext_vector_type(8)));
typedef float    f32x4  __attribute__((ext_vector_type(4)));
typedef unsigned u32x2  __attribute__((ext_vector_type(2)));

#define WF1_N 262144
#define WF1_SLICES 64
#define WF1_SLICE 4096

__device__ __forceinline__ float block_reduce_256(float v, float* red, int t) {
    red[t] = v; __syncthreads();
    for (int o = 128; o > 0; o >>= 1) {
        if (t < o) red[t] += red[t + o];
        __syncthreads();
    }
    float r = red[0]; __syncthreads();
    return r;
}

__device__ __forceinline__ float wave_sum64(float v) {
#pragma unroll
    for (int o = 32; o > 0; o >>= 1) v += __shfl_xor(v, o);
    return v;
}

__device__ __forceinline__ unsigned pk16(float a, float b) {
    half2v h;
    h[0] = (_Float16)a;
    h[1] = (_Float16)b;
    return __builtin_bit_cast(unsigned, h);
}

// ---------------- stage A: wf1 partial |sum| + small tensors complete ------
__global__ void tern_stageA(const float* __restrict__ w1,
                            const float* __restrict__ w2,
                            const float* __restrict__ wf1,
                            const float* __restrict__ wf2,
                            _Float16* __restrict__ tw1f,
                            _Float16* __restrict__ tw2f,
                            float* __restrict__ twf2,
                            float* __restrict__ part_sum) {
    __shared__ float red[256];
    const int t = threadIdx.x;
    const int bid = blockIdx.x;

    if (bid < WF1_SLICES) {
        const float4* src = reinterpret_cast<const float4*>(wf1 + (size_t)bid * WF1_SLICE);
        float s = 0.f;
#pragma unroll
        for (int j = 0; j < 4; ++j) {
            const float4 v = src[t + j * 256];
            s += fabsf(v.x) + fabsf(v.y) + fabsf(v.z) + fabsf(v.w);
        }
        const float tot = block_reduce_256(s, red, t);
        if (t == 0) part_sum[bid] = tot;
        return;
    }

    const float* w;
    int n;
    const int which = bid - WF1_SLICES;  // 0:w1 1:w2 2:wf2
    switch (which) {
        case 0: w = w1;  n = 432;  break;
        case 1: w = w2;  n = 4608; break;
        default: w = wf2; n = 1280; break;
    }
    float s = 0.f;
    for (int i = t; i < n; i += 256) s += fabsf(w[i]);
    const float delta = 0.7f * block_reduce_256(s, red, t) / (float)n;
    float sa = 0.f, cnt = 0.f;
    for (int i = t; i < n; i += 256) {
        float a = fabsf(w[i]);
        if (a > delta) { sa += a; cnt += 1.f; }
    }
    const float tot_sa = block_reduce_256(sa, red, t);
    const float tot_cnt = block_reduce_256(cnt, red, t);
    const float alpha = tot_sa / fmaxf(tot_cnt, 1.0f);

    switch (which) {
        case 0:
            // conv1 B-frags (K=16): o=(m*64+l)*4+j; rho=m*4+(l>>4); co=l&15
            for (int o = t; o < 768; o += 256) {
                int j = o & 3;
                int l = (o >> 2) & 63;
                int m = o >> 8;
                int rho = m * 4 + (l >> 4);
                int co = l & 15;
                float v = 0.f;
                if (rho < 9 && j < 3) {
                    float wv = w1[co * 27 + (rho / 3) * 9 + (rho % 3) * 3 + j];
                    v = (fabsf(wv) > delta) ? copysignf(alpha, wv) : 0.f;
                }
                tw1f[o] = (_Float16)v;
            }
            break;
        case 1:
            // conv2 B-frags (K=16): o=((s*2+nt)*64+l)*4+j; ci=(l>>4)*4+j;
            // co=(l&15)+nt*16
            for (int o = t; o < 4608; o += 256) {
                int j  = o & 3;
                int ll = (o >> 2) & 63;
                int nt = (o >> 8) & 1;
                int s9 = o >> 9;
                int ci = (ll >> 4) * 4 + j;
                int co = (ll & 15) + nt * 16;
                float wv = w2[(co * 16 + ci) * 9 + s9];
                float v = (fabsf(wv) > delta) ? copysignf(alpha, wv) : 0.f;
                tw2f[o] = (_Float16)v;
            }
            break;
        default:
            for (int o = t; o < 1280; o += 256) {
                float wv = wf2[o];
                twf2[o] = (fabsf(wv) > delta) ? copysignf(alpha, wv) : 0.f;
            }
            break;
    }
}

// ---------------- stage B: delta + masked partials + packed SIGN write -----
// twf1 = sign(w)*mask f16, FRAGMENT-PACKED:
//   f(n,k) = (k/32)*4096 + (n/16)*512 + ((k>>3)&3)*128 + (n&15)*8 + (k&7)
__global__ void tern_stageB(const float* __restrict__ wf1,
                            const float* __restrict__ part_sum,
                            float* __restrict__ part_sa,
                            float* __restrict__ part_cnt,
                            _Float16* __restrict__ twf1) {
    __shared__ float red[256];
    const int t = threadIdx.x;
    const int bid = blockIdx.x;

    float v = (t < WF1_SLICES) ? part_sum[t] : 0.f;
    const float delta = 0.7f * block_reduce_256(v, red, t) / (float)WF1_N;

    const float4* src = reinterpret_cast<const float4*>(wf1 + (size_t)bid * WF1_SLICE);
    float sa = 0.f, cnt = 0.f;
#pragma unroll
    for (int j = 0; j < 4; ++j) {
        const float4 w4 = src[t + j * 256];
        half4 hv;
        float a;
        a = fabsf(w4.x); if (a > delta) { sa += a; cnt += 1.f; }
        hv[0] = (_Float16)((fabsf(w4.x) > delta) ? copysignf(1.0f, w4.x) : 0.f);
        a = fabsf(w4.y); if (a > delta) { sa += a; cnt += 1.f; }
        hv[1] = (_Float16)((fabsf(w4.y) > delta) ? copysignf(1.0f, w4.y) : 0.f);
        a = fabsf(w4.z); if (a > delta) { sa += a; cnt += 1.f; }
        hv[2] = (_Float16)((fabsf(w4.z) > delta) ? copysignf(1.0f, w4.z) : 0.f);
        a = fabsf(w4.w); if (a > delta) { sa += a; cnt += 1.f; }
        hv[3] = (_Float16)((fabsf(w4.w) > delta) ? copysignf(1.0f, w4.w) : 0.f);
        // flat source index o (floats): 4 consecutive k of one n, k%4==0
        const int o = bid * WF1_SLICE + (t + j * 256) * 4;
        const int n = o >> 11, k = o & 2047;
        const int dst = ((k >> 5) << 12) + ((n >> 4) << 9) +
                        (((k >> 3) & 3) << 7) + ((n & 15) << 3) + (k & 7);
        *reinterpret_cast<half4*>(twf1 + dst) = hv;
    }
    const float tot_sa = block_reduce_256(sa, red, t);
    const float tot_cnt = block_reduce_256(cnt, red, t);
    if (t == 0) { part_sa[bid] = tot_sa; part_cnt[bid] = tot_cnt; }
}

// ---------------- fused conv1(MFMA)+pool + conv2(MFMA)+pool ----------------
// H1P=18: pixel stride 9 dwords (odd) -> conv2 A-read bank conflicts 2-way (free).
#define H1P 18
#define PSZ 3472          // 3*34*34=3468 + 4 pad f16 (6944 B, /16 ok)
#define H1SZ (18*18*H1P)  // 5832 f16 = 11664 B (/16 ok)

__global__ __launch_bounds__(256, 5)
void conv12_kernel(const float* __restrict__ x,      // [B,3,32,32]
                   const float* __restrict__ b1,     // [16]
                   const float* __restrict__ b2,     // [32]
                   const _Float16* __restrict__ tw1f,// [3][64][4] f16 B-frags
                   const _Float16* __restrict__ tw2f,// [9][2][64][4] f16 B-frags
                   _Float16* __restrict__ h2p) {     // [B,2048] f16
    __shared__ __align__(16) _Float16 PA[PSZ];          // planar f16 [3][34][34]
    __shared__ __align__(16) _Float16 PB[PSZ];          // PB[i] = PA[i+1]
    __shared__ __align__(16) _Float16 h1s[H1SZ];        // (y*18+x)*18 + ci
    __shared__ __align__(16) _Float16 h2s[2048];        // co*64 + py*8 + px
    __shared__ float b1s[16], b2s[32];

    const int t = threadIdx.x;
    const int b = blockIdx.x;
    const int wid = t >> 6, l = t & 63;

    // issue x loads FIRST (3x float4, coalesced) so HBM latency hides
    // under the zero phase
    float4 xv4[3];
    {
        const float4* xb4 = reinterpret_cast<const float4*>(x + (size_t)b * 3072);
#pragma unroll
        for (int j = 0; j < 3; ++j) xv4[j] = xb4[t + j * 256];
    }
    // conv1 B-frags (L2-resident)
    half4 bfr1[3];
#pragma unroll
    for (int m = 0; m < 3; ++m)
        bfr1[m] = *reinterpret_cast<const half4*>(tw1f + (size_t)(m * 64 + l) * 4);
    if (t < 16) b1s[t] = b1[t];
    if (t < 32) b2s[t] = b2[t];

    // zero LDS via float4 (halos / garbage-tap safety)
    {
        const float4 z = {0.f, 0.f, 0.f, 0.f};
        float4* pa4 = reinterpret_cast<float4*>(PA);
        float4* pb4 = reinterpret_cast<float4*>(PB);
        float4* h14 = reinterpret_cast<float4*>(h1s);
        for (int i = t; i < PSZ * 2 / 16; i += 256) { pa4[i] = z; pb4[i] = z; }
        for (int i = t; i < H1SZ * 2 / 16; i += 256) h14[i] = z;
    }
    __syncthreads();

    // phase 1: stage x -> planar f16 PA + shifted copy PB (parity-aware u32)
    {
#pragma unroll
        for (int j = 0; j < 3; ++j) {
            const int f = t + j * 256;           // float4 group id, 768 total
            const int c = f >> 8, rem = f & 255;
            const int iy = rem >> 3, ix = (rem & 7) << 2;
            const int idx = ((c * 34) + iy + 1) * 34 + 1 + ix;
            const float4 v = xv4[j];
            const unsigned w0 = __builtin_bit_cast(unsigned, __builtin_amdgcn_cvt_pkrtz(v.x, v.y));
            const unsigned w1 = __builtin_bit_cast(unsigned, __builtin_amdgcn_cvt_pkrtz(v.z, v.w));
            const half2v h0 = __builtin_bit_cast(half2v, w0);
            const half2v h1 = __builtin_bit_cast(half2v, w1);
            *reinterpret_cast<unsigned*>(&PB[idx - 1]) = w0;
            *reinterpret_cast<unsigned*>(&PB[idx + 1]) = w1;
            PA[idx] = h0[0];
            *reinterpret_cast<unsigned*>(&PA[idx + 1]) = (w0 >> 16) | (w1 << 16);
            PA[idx + 3] = h1[1];
        }
    }
    __syncthreads();

    // phase 2: conv1 via 3x chained 16x16x16 MFMA (K-rows (c,ky) x 4 taps)
    {
        const int r15 = l & 15, g = l >> 4;
        const int p = r15 & 1;
        int laneIdx[3];
#pragma unroll
        for (int m = 0; m < 3; ++m) {
            int rho = m * 4 + g;
            if (rho > 8) rho = 0;  // dead rows: B is zero there, any finite read ok
            const int c = rho / 3, ky = rho % 3;
            laneIdx[m] = ((c * 34 + ky) * 34 + r15 - p) >> 1;
        }
        const unsigned* basep = p ? reinterpret_cast<const unsigned*>(PB)
                                  : reinterpret_cast<const unsigned*>(PA);
        const float bia = b1s[r15];

#pragma unroll 1
        for (int i = 0; i < 8; ++i) {
            const int P = wid * 8 + i;
            const int py = P >> 1, xh = P & 1;
            const int x0 = xh * 16;
            f32x4 accA = {0.f, 0.f, 0.f, 0.f};
            f32x4 accB = {0.f, 0.f, 0.f, 0.f};
#pragma unroll
            for (int h2 = 0; h2 < 2; ++h2) {
                const int y = 2 * py + h2;
                const int uoff = (y * 34 + x0) >> 1;
                f32x4 acc = {0.f, 0.f, 0.f, 0.f};
#pragma unroll
                for (int m = 0; m < 3; ++m) {
                    const unsigned* q = basep + laneIdx[m] + uoff;
                    u32x2 d;
                    d.x = q[0];
                    d.y = q[1];
                    const half4 a = __builtin_bit_cast(half4, d);
                    acc = __builtin_amdgcn_mfma_f32_16x16x16f16(a, bfr1[m], acc, 0, 0, 0);
                }
                if (h2 == 0) accA = acc; else accB = acc;
            }
            // 2x2 maxpool on regs (x = g*4 + reg), then bias+relu
            float e0 = fmaxf(fmaxf(accA[0], accA[1]), fmaxf(accB[0], accB[1]));
            float e1 = fmaxf(fmaxf(accA[2], accA[3]), fmaxf(accB[2], accB[3]));
            e0 = fmaxf(e0 + bia, 0.f);
            e1 = fmaxf(e1 + bia, 0.f);
            const int px0 = xh * 8 + g * 2;
            const int pix = (py + 1) * 18 + (px0 + 1);
            h1s[pix * H1P + r15]       = (_Float16)e0;
            h1s[(pix + 1) * H1P + r15] = (_Float16)e1;
        }
    }

    // conv2 B-frags (global, per-lane 8B, coalesced, L2-resident)
    half4 bfr[9][2];
#pragma unroll
    for (int s = 0; s < 9; ++s)
#pragma unroll
        for (int nt = 0; nt < 2; ++nt)
            bfr[s][nt] = *reinterpret_cast<const half4*>(
                tw2f + (size_t)((s * 2 + nt) * 64 + l) * 4);
    __syncthreads();

    // phase 3: conv2 (9-shift MFMA) + bias + relu + pool
    {
        const int xq = l & 15, g = l >> 4;
        const unsigned* h1u = reinterpret_cast<const unsigned*>(h1s);
        float sav[2][2];
#pragma unroll
        for (int yy = 0; yy < 4; ++yy) {
            const int y = wid * 4 + yy;
            // per-lane base; all 9 taps are constant dword offsets from here
            const unsigned* qb = h1u + (y * 18 + xq) * 9 + g * 2;
            f32x4 acc0 = {0.f, 0.f, 0.f, 0.f};
            f32x4 acc1 = {0.f, 0.f, 0.f, 0.f};
#pragma unroll
            for (int s = 0; s < 9; ++s) {
                const int dy = s / 3, dx = s % 3;
                const int off = (dy * 18 + dx) * 9;
                u32x2 d;
                d.x = qb[off];
                d.y = qb[off + 1];
                const half4 a = __builtin_bit_cast(half4, d);
                acc0 = __builtin_amdgcn_mfma_f32_16x16x16f16(a, bfr[s][0], acc0, 0, 0, 0);
                acc1 = __builtin_amdgcn_mfma_f32_16x16x16f16(a, bfr[s][1], acc1, 0, 0, 0);
            }
            // x-pool: lane regs are pixels x = g*4 + r
            const float p00 = fmaxf(acc0[0], acc0[1]);
            const float p01 = fmaxf(acc0[2], acc0[3]);
            const float p10 = fmaxf(acc1[0], acc1[1]);
            const float p11 = fmaxf(acc1[2], acc1[3]);
            if ((yy & 1) == 0) {
                sav[0][0] = p00; sav[0][1] = p01;
                sav[1][0] = p10; sav[1][1] = p11;
            } else {
                const int py = (wid * 4 + yy) >> 1;
                const float v00 = fmaxf(fmaxf(sav[0][0], p00) + b2s[xq], 0.f);
                const float v01 = fmaxf(fmaxf(sav[0][1], p01) + b2s[xq], 0.f);
                const float v10 = fmaxf(fmaxf(sav[1][0], p10) + b2s[xq + 16], 0.f);
                const float v11 = fmaxf(fmaxf(sav[1][1], p11) + b2s[xq + 16], 0.f);
                unsigned* h2u = reinterpret_cast<unsigned*>(h2s);
                h2u[xq * 32 + py * 4 + g]        = pk16(v00, v01);
                h2u[(xq + 16) * 32 + py * 4 + g] = pk16(v10, v11);
            }
        }
    }
    __syncthreads();

    // phase 4: h2s -> global (coalesced 16B/thread)
    {
        const float4 v = reinterpret_cast<const float4*>(h2s)[t];
        reinterpret_cast<float4*>(h2p + (size_t)b * 2048)[t] = v;
    }
}

// ---------------- fc1 (MFMA f16, packed-B + LDS-staged A) + fc2 fused ------
// grid = B/16 = 256 blocks x 1024 threads (16 waves = 4 K-chunks x 4 N-groups).
// B (twf1) is fragment-packed -> per-(kc,NT) load is twf1[kc*4096+NT*512+l*8],
// lane-linear 16B/lane (1KB coalesced wave-load from L2). A staged in LDS.
#define FC_PAD 8  // As row stride 1032 f16 = 516 dwords -> 2-way conflicts (free)

__global__ __launch_bounds__(1024, 2)
void fc_kernel(const _Float16* __restrict__ h2p,   // [B,2048]
               const _Float16* __restrict__ twf1,  // fragment-packed signs
               const float* __restrict__ part_sa,  // [64]
               const float* __restrict__ part_cnt, // [64]
               const float* __restrict__ bf1,      // [128]
               const float* __restrict__ twf2,     // [10][128]
               const float* __restrict__ bf2,      // [10]
               float* __restrict__ out) {          // [B,10]
    __shared__ __align__(16) _Float16 As[16][1024 + FC_PAD];  // 33024 B
    __shared__ float red[4][3][2][256];                       // 24576 B
    __shared__ float Hs[16][132];                             // 8448 B

    const int t = threadIdx.x;
    const int wid = t >> 6, l = t & 63;
    const int kq = wid & 3, ng = wid >> 2;
    const int lx = l & 15, g = l >> 4;
    const int m0 = blockIdx.x * 16;

    // alpha for wf1 (f32 exact; cheap, all waves)
    const float alphaW = wave_sum64(part_sa[l]) / fmaxf(wave_sum64(part_cnt[l]), 1.0f);

    f32x4 acc[2];
    acc[0] = (f32x4){0.f, 0.f, 0.f, 0.f};
    acc[1] = (f32x4){0.f, 0.f, 0.f, 0.f};

    const int stg_r = t >> 7;            // 0..7
    const int stg_c = (t & 127) * 8;     // 0..1016

#pragma unroll
    for (int h = 0; h < 2; ++h) {
        if (h) __syncthreads();  // previous half's reads done before overwrite
        // stage 16 rows x 1024 k, fully coalesced (128 thr/row, 16B each)
#pragma unroll
        for (int p = 0; p < 2; ++p) {
            const int r = stg_r + p * 8;
            *reinterpret_cast<float4*>(&As[r][stg_c]) =
                *reinterpret_cast<const float4*>(
                    h2p + (size_t)(m0 + r) * 2048 + h * 1024 + stg_c);
        }
        __syncthreads();
#pragma unroll
        for (int it = 0; it < 8; ++it) {
            const int kk = kq * 256 + it * 32;
            const int kc = (h * 1024 + kk) >> 5;   // global 32-k chunk
            const half8 a = *reinterpret_cast<const half8*>(&As[lx][kk + g * 8]);
#pragma unroll
            for (int nt = 0; nt < 2; ++nt) {
                const half8 bb = *reinterpret_cast<const half8*>(
                    twf1 + ((size_t)kc << 12) + ((ng * 2 + nt) << 9) + l * 8);
                acc[nt] = __builtin_amdgcn_mfma_f32_16x16x32_f16(a, bb, acc[nt], 0, 0, 0);
            }
        }
    }

    // single-shot partial dump: kq=1..3 write, kq=0 sums
    if (kq != 0) {
#pragma unroll
        for (int nt = 0; nt < 2; ++nt)
            *reinterpret_cast<f32x4*>(&red[ng][kq - 1][nt][l * 4]) = acc[nt];
    }
    __syncthreads();
    if (kq == 0) {
#pragma unroll
        for (int nt = 0; nt < 2; ++nt) {
#pragma unroll
            for (int q = 0; q < 3; ++q)
                acc[nt] += *reinterpret_cast<const f32x4*>(&red[ng][q][nt][l * 4]);
            const int col = ng * 32 + nt * 16 + lx;
            const float bias = bf1[col];
#pragma unroll
            for (int r = 0; r < 4; ++r)
                Hs[g * 4 + r][col] = fmaxf(acc[nt][r] * alphaW + bias, 0.f);
        }
    }
    __syncthreads();

    // fc2: 160 outputs (16 rows x 10)
    if (t < 160) {
        const int m = t / 10, n = t % 10;
        float a = bf2[n];
#pragma unroll 8
        for (int k = 0; k < 128; ++k) a += Hs[m][k] * twf2[n * 128 + k];
        out[(size_t)(m0 + m) * 10 + n] = a;
    }
}

// ---------------------------------------------------------------------------
extern "C" void kernel_launch(void* const* d_in, const int* in_sizes, int n_in,
                              void* d_out, int out_size, void* d_ws, size_t ws_size,
                              hipStream_t stream) {
    const float* x   = (const float*)d_in[0];
    const float* w1  = (const float*)d_in[1];
    const float* b1  = (const float*)d_in[2];
    const float* w2  = (const float*)d_in[3];
    const float* b2  = (const float*)d_in[4];
    const float* wf1 = (const float*)d_in[5];
    const float* bf1 = (const float*)d_in[6];
    const float* wf2 = (const float*)d_in[7];
    const float* bf2 = (const float*)d_in[8];
    float* out = (float*)d_out;
    const int B = in_sizes[0] / (3 * 32 * 32);  // 4096

    char* ws = (char*)d_ws;
    _Float16*  tw1f  = (_Float16*)(ws + 0);
    _Float16*  tw2f  = (_Float16*)(ws + 1536);
    _Float16*  twf1  = (_Float16*)(ws + 10752);
    float*     twf2  = (float*)(ws + 535040);
    _Float16*  h2p   = (_Float16*)(ws + 540160);
    float*     part_sum = (float*)(ws + 17317376);
    float*     part_sa  = part_sum + 64;
    float*     part_cnt = part_sa + 64;

    tern_stageA<<<WF1_SLICES + 3, 256, 0, stream>>>(w1, w2, wf1, wf2,
                                                    tw1f, tw2f, twf2, part_sum);
    tern_stageB<<<WF1_SLICES, 256, 0, stream>>>(wf1, part_sum, part_sa, part_cnt, twf1);
    conv12_kernel<<<B, 256, 0, stream>>>(x, b1, b2, tw1f, tw2f, h2p);
    fc_kernel<<<B / 16, 1024, 0, stream>>>(h2p, twf1, part_sa, part_cnt,
                                           bf1, twf2, bf2, out);
}